// Round 7
// baseline (83.478 us; speedup 1.0000x reference)
//
#include <hip/hip_runtime.h>

#define NN 16
constexpr int BB = 32, CIN = 64, HH = 112, WW = 112;
constexpr int HWC = HH * WW;          // 12544
constexpr int COUT = 128, HW2 = 56 * 56;
constexpr int NE = 64;
constexpr int NQ = HWC / 4;           // 3136 quads per image
constexpr int HQ = NQ / 2;            // 1568 quads per image-half
constexpr int CPB = 8;                // channels per conv block
constexpr int PF4 = COUT * HW2 / 4;   // 100352 float4 per batch
constexpr int SBPB = 25;              // scale blocks per batch

// ---- Kernel 1: sequential-stream 1x1 conv + segment scatter ----
// Block = (image b, half h, channel-group cg of 8). Outer loop over the 8
// channels; inner loop walks the channel plane sequentially (4KB per block
// iteration) -> long DRAM row runs. Per-thread register partials (6-7 quads),
// then one scatter pass. row/col/cnt stats are contributed by cg 0/1/2.
__global__ __launch_bounds__(256, 2) void k_conv_seg(
    const float* __restrict__ Bfor, const int* __restrict__ seg,
    const float* __restrict__ convw, float* __restrict__ part)
{
    __shared__ float acc8[8 * 80];      // [replica][node*5+st], bank-skewed
    const int tid = threadIdx.x;
    const int bid = blockIdx.x;
    const int b   = bid >> 4;
    const int h   = (bid >> 3) & 1;
    const int cg  = bid & 7;

    for (int i = tid; i < 8 * 80; i += 256) acc8[i] = 0.f;
    __syncthreads();

    // quads (within half): tid + k*256, k<6 for all, k=6 for tid<32 (1568=6*256+32)
    float4 a[7];
    #pragma unroll
    for (int k = 0; k < 7; ++k) a[k] = make_float4(0.f, 0.f, 0.f, 0.f);

    const float* bbase = Bfor + (size_t)(b * CIN + cg * CPB) * HWC + (size_t)h * HQ * 4;
    #pragma unroll
    for (int c = 0; c < CPB; ++c) {
        const float wc = convw[cg * CPB + c];
        const float* pl = bbase + (size_t)c * HWC + tid * 4;
        float4 v[7];
        #pragma unroll
        for (int k = 0; k < 6; ++k)
            v[k] = *reinterpret_cast<const float4*>(pl + k * 1024);
        if (tid < 32) v[6] = *reinterpret_cast<const float4*>(pl + 6 * 1024);
        #pragma unroll
        for (int k = 0; k < 6; ++k) {
            a[k].x = fmaf(v[k].x, wc, a[k].x);
            a[k].y = fmaf(v[k].y, wc, a[k].y);
            a[k].z = fmaf(v[k].z, wc, a[k].z);
            a[k].w = fmaf(v[k].w, wc, a[k].w);
        }
        if (tid < 32) {
            a[6].x = fmaf(v[6].x, wc, a[6].x);
            a[6].y = fmaf(v[6].y, wc, a[6].y);
            a[6].z = fmaf(v[6].z, wc, a[6].z);
            a[6].w = fmaf(v[6].w, wc, a[6].w);
        }
    }

    // ---- scatter phase ----
    const int* segb = seg + (size_t)b * HWC + (size_t)h * HQ * 4;
    const int rep = tid & 7;
    float* ar = &acc8[rep * 80];
    const int nk = (tid < 32) ? 7 : 6;
    for (int k = 0; k < nk; ++k) {
        const int q = tid + k * 256;              // quad within half
        const int p = h * HQ * 4 + q * 4;         // pixel index in image
        const int4 sg = *reinterpret_cast<const int4*>(segb + q * 4);
        atomicAdd(ar + sg.x * 5 + 2, a[k].x);
        atomicAdd(ar + sg.y * 5 + 2, a[k].y);
        atomicAdd(ar + sg.z * 5 + 2, a[k].z);
        atomicAdd(ar + sg.w * 5 + 2, a[k].w);
        if (cg == 0) {                            // row sums
            const float row = (float)(p / WW);
            atomicAdd(ar + sg.x * 5 + 0, row);
            atomicAdd(ar + sg.y * 5 + 0, row);
            atomicAdd(ar + sg.z * 5 + 0, row);
            atomicAdd(ar + sg.w * 5 + 0, row);
        } else if (cg == 1) {                     // col sums
            const float col0 = (float)(p % WW);
            atomicAdd(ar + sg.x * 5 + 1, col0);
            atomicAdd(ar + sg.y * 5 + 1, col0 + 1.f);
            atomicAdd(ar + sg.z * 5 + 1, col0 + 2.f);
            atomicAdd(ar + sg.w * 5 + 1, col0 + 3.f);
        } else if (cg == 2) {                     // counts
            atomicAdd(ar + sg.x * 5 + 3, 1.f);
            atomicAdd(ar + sg.y * 5 + 3, 1.f);
            atomicAdd(ar + sg.z * 5 + 3, 1.f);
            atomicAdd(ar + sg.w * 5 + 3, 1.f);
        }
    }
    __syncthreads();

    if (tid < 64) {
        const int node = tid >> 2, st = tid & 3;
        float v = 0.f;
        #pragma unroll
        for (int r = 0; r < 8; ++r) v += acc8[r * 80 + node * 5 + st];
        part[bid * 64 + node * 4 + st] = v;
    }
}

// ------- Kernel 2: fused graph stage (redundant per block) + broadcast scale
__global__ __launch_bounds__(256) void k_graph_scale(
    const float* __restrict__ part, const int* __restrict__ src,
    const int* __restrict__ dst,  const float* __restrict__ convb,
    const float* __restrict__ W1, const float* __restrict__ b1,
    const float* __restrict__ W2, const float* __restrict__ b2,
    const float* __restrict__ fcw, const float* __restrict__ fcb,
    const float* __restrict__ Bfon, float* __restrict__ out)
{
    const int b    = blockIdx.x / SBPB;
    const int blkb = blockIdx.x % SBPB;
    const int tid  = threadIdx.x;

    __shared__ float X[NN][4];
    __shared__ float A[NN][NN];
    __shared__ float nrm[NN];
    __shared__ float h1s[NN][32];
    __shared__ float agg[NN][32];
    __shared__ float gpart[2][COUT];
    __shared__ float Gs[COUT];

    // ---- Phase A: tiny graph network (redundant across SBPB blocks) ----
    if (tid < 64) {        // reduce the 16 conv-block partials of image b
        float v = 0.f;
        #pragma unroll
        for (int j = 0; j < 16; ++j) v += part[(b * 16 + j) * 64 + tid];
        X[tid >> 2][tid & 3] = v;
    }
    for (int i = tid; i < NN * NN; i += 256) ((float*)A)[i] = 0.f;
    __syncthreads();

    if (tid < NN) {        // raw sums -> features (conv bias folded in)
        const float cnt = X[tid][3];
        const float cs  = fmaxf(cnt, 1.f);
        X[tid][0] = X[tid][0] / cs;
        X[tid][1] = X[tid][1] / cs;
        X[tid][2] = (X[tid][2] + cnt * convb[0]) / cs;
    }
    __syncthreads();

    // normalize feature cols 2,3 across nodes (mean, std ddof=1)
    if (tid < 2) {
        const int c = 2 + tid;
        float mu = 0.f;
        for (int i = 0; i < NN; ++i) mu += X[i][c];
        mu *= (1.f / NN);
        float var = 0.f;
        for (int i = 0; i < NN; ++i) { const float d = X[i][c] - mu; var = fmaf(d, d, var); }
        var *= (1.f / (NN - 1));
        const float inv = 1.f / (sqrtf(var) + 1.f);
        for (int i = 0; i < NN; ++i) X[i][c] = (X[i][c] - mu) * inv;
    }
    // build adjacency (idempotent set-to-1)
    if (tid >= 64 && tid < 64 + NE) {
        const int e = tid - 64;
        const int s = src[b * NE + e], d = dst[b * NE + e];
        A[s][d] = 1.f;
        A[d][s] = 1.f;
    }
    __syncthreads();

    if (tid < NN) {
        float rs = 0.f;
        for (int j = 0; j < NN; ++j) rs += A[tid][j];
        nrm[tid] = 1.f / sqrtf(fmaxf(rs, 1.f));
    }
    __syncthreads();

    if (tid < NN * 4) {    // agg1 (16x4)
        const int i = tid >> 2, k = tid & 3;
        float s = 0.f;
        for (int j = 0; j < NN; ++j) s = fmaf(A[i][j] * nrm[j], X[j][k], s);
        agg[i][k] = s;
    }
    __syncthreads();

    for (int t = tid; t < NN * 32; t += 256) {   // h1 (16x32)
        const int i = t >> 5, f = t & 31;
        float s = 0.f;
        #pragma unroll
        for (int k = 0; k < 4; ++k) s = fmaf(agg[i][k], W1[k * 32 + f], s);
        h1s[i][f] = fmaxf(fmaf(nrm[i], s, b1[f]), 0.f);
    }
    __syncthreads();

    for (int t = tid; t < NN * 32; t += 256) {   // agg2 (16x32)
        const int i = t >> 5, k = t & 31;
        float s = 0.f;
        for (int j = 0; j < NN; ++j) s = fmaf(A[i][j] * nrm[j], h1s[j][k], s);
        agg[i][k] = s;
    }
    __syncthreads();

    {   // h2 + FC, i-range split across 2 half-blocks
        const int f = tid & 127, half = tid >> 7;
        float g = 0.f;
        const float bf = b2[f];
        for (int i = half * 8; i < half * 8 + 8; ++i) {
            float s = 0.f;
            #pragma unroll
            for (int k = 0; k < 32; ++k) s = fmaf(agg[i][k], W2[k * COUT + f], s);
            g = fmaf(fcw[i], fmaxf(fmaf(nrm[i], s, bf), 0.f), g);
        }
        gpart[half][f] = g;
    }
    __syncthreads();
    if (tid < COUT) Gs[tid] = gpart[0][tid] + gpart[1][tid] + fcb[0];
    __syncthreads();

    // ---- Phase B: out[b,c,:,:] = Gs[c] * B_fon[b,c,:,:] (this block's slice)
    const float4* bf4 = reinterpret_cast<const float4*>(Bfon) + (size_t)b * PF4;
    float4*       ob4 = reinterpret_cast<float4*>(out)        + (size_t)b * PF4;
    for (int t = blkb * 256 + tid; t < PF4; t += SBPB * 256) {
        const float4 v = bf4[t];
        const float  g = Gs[t / (HW2 / 4)];   // 784 float4 per (b,c) plane
        ob4[t] = make_float4(v.x * g, v.y * g, v.z * g, v.w * g);
    }
}

extern "C" void kernel_launch(void* const* d_in, const int* in_sizes, int n_in,
                              void* d_out, int out_size, void* d_ws, size_t ws_size,
                              hipStream_t stream)
{
    const float* Bfor  = (const float*)d_in[0];
    const float* Bfon  = (const float*)d_in[1];
    const int*   seg   = (const int*)d_in[2];
    const int*   src   = (const int*)d_in[3];
    const int*   dst   = (const int*)d_in[4];
    const float* convw = (const float*)d_in[5];
    const float* convb = (const float*)d_in[6];
    const float* W1    = (const float*)d_in[7];
    const float* b1    = (const float*)d_in[8];
    const float* W2    = (const float*)d_in[9];
    const float* b2    = (const float*)d_in[10];
    const float* fcw   = (const float*)d_in[11];
    const float* fcb   = (const float*)d_in[12];

    float* part = (float*)d_ws;           // 512 blocks x 64 floats = 128 KB
    float* out  = (float*)d_out;

    k_conv_seg<<<BB * 16, 256, 0, stream>>>(Bfor, seg, convw, part);
    k_graph_scale<<<BB * SBPB, 256, 0, stream>>>(part, src, dst, convb,
                                                 W1, b1, W2, b2, fcw, fcb,
                                                 Bfon, out);
}

// Round 8
// 72.549 us; speedup vs baseline: 1.1506x; 1.1506x over previous
//
#include <hip/hip_runtime.h>

#define NN 16
constexpr int BB = 32, CIN = 64, HH = 112, WW = 112;
constexpr int HWC = HH * WW;          // 12544
constexpr int COUT = 128, HW2 = 56 * 56;
constexpr int NE = 64;
constexpr int NQ = HWC / 4;           // 3136 quads per image (= 12*256 + 64)
constexpr int CPB = 8;                // channels per conv block
constexpr int NCG = CIN / CPB;        // 8 channel-groups per image
constexpr int PF4 = COUT * HW2 / 4;   // 100352 float4 per batch
constexpr int SBPB = 25;              // scale blocks per batch

// ---- Kernel 1: sequential-stream 1x1 conv + segment scatter (spill-free) --
// Block = (image b, channel-group cg of 8 contiguous channels). The block
// walks its 8 planes (400 KB contiguous) front-to-back in 4KB wave chunks.
// Thread owns 13 quads (tail iter 12 only for tid<64). ALL loops statically
// unrolled -> a[13]/v[13] stay in VGPRs (R7's runtime-bound spill fixed).
// row/col/cnt stats contributed once, by cg 0/1/2 respectively.
__global__ __launch_bounds__(256) void k_conv_seg(
    const float* __restrict__ Bfor, const int* __restrict__ seg,
    const float* __restrict__ convw, float* __restrict__ part)
{
    __shared__ float acc8[8 * 80];      // [replica][node*5+st], bank-skewed
    const int tid = threadIdx.x;
    const int bid = blockIdx.x;
    const int b   = bid >> 3;
    const int cg  = bid & 7;

    for (int i = tid; i < 8 * 80; i += 256) acc8[i] = 0.f;

    float wreg[CPB];
    #pragma unroll
    for (int c = 0; c < CPB; ++c) wreg[c] = convw[cg * CPB + c];
    __syncthreads();

    float4 a[13];
    #pragma unroll
    for (int k = 0; k < 13; ++k) a[k] = make_float4(0.f, 0.f, 0.f, 0.f);

    const float* base = Bfor + (size_t)(b * CIN + cg * CPB) * HWC;
    #pragma unroll
    for (int c = 0; c < CPB; ++c) {
        const float wc = wreg[c];
        const float* pl = base + (size_t)c * HWC + tid * 4;
        float4 v[13];
        #pragma unroll
        for (int k = 0; k < 13; ++k)
            if (k < 12 || tid < 64)
                v[k] = *reinterpret_cast<const float4*>(pl + k * 1024);
        #pragma unroll
        for (int k = 0; k < 13; ++k)
            if (k < 12 || tid < 64) {
                a[k].x = fmaf(v[k].x, wc, a[k].x);
                a[k].y = fmaf(v[k].y, wc, a[k].y);
                a[k].z = fmaf(v[k].z, wc, a[k].z);
                a[k].w = fmaf(v[k].w, wc, a[k].w);
            }
    }

    // ---- scatter phase (static unroll, k compile-time) ----
    const int* segb = seg + (size_t)b * HWC;
    const int rep = tid & 7;
    float* ar = &acc8[rep * 80];
    #pragma unroll
    for (int k = 0; k < 13; ++k) {
        if (k < 12 || tid < 64) {
            const int q = tid + k * 256;          // quad id in image
            const int p = q * 4;
            const int4 sg = *reinterpret_cast<const int4*>(segb + p);
            atomicAdd(ar + sg.x * 5 + 2, a[k].x);
            atomicAdd(ar + sg.y * 5 + 2, a[k].y);
            atomicAdd(ar + sg.z * 5 + 2, a[k].z);
            atomicAdd(ar + sg.w * 5 + 2, a[k].w);
            if (cg == 0) {                        // row sums (WW%4==0)
                const float row = (float)(p / WW);
                atomicAdd(ar + sg.x * 5 + 0, row);
                atomicAdd(ar + sg.y * 5 + 0, row);
                atomicAdd(ar + sg.z * 5 + 0, row);
                atomicAdd(ar + sg.w * 5 + 0, row);
            } else if (cg == 1) {                 // col sums
                const float col0 = (float)(p % WW);
                atomicAdd(ar + sg.x * 5 + 1, col0);
                atomicAdd(ar + sg.y * 5 + 1, col0 + 1.f);
                atomicAdd(ar + sg.z * 5 + 1, col0 + 2.f);
                atomicAdd(ar + sg.w * 5 + 1, col0 + 3.f);
            } else if (cg == 2) {                 // counts
                atomicAdd(ar + sg.x * 5 + 3, 1.f);
                atomicAdd(ar + sg.y * 5 + 3, 1.f);
                atomicAdd(ar + sg.z * 5 + 3, 1.f);
                atomicAdd(ar + sg.w * 5 + 3, 1.f);
            }
        }
    }
    __syncthreads();

    if (tid < 64) {
        const int node = tid >> 2, st = tid & 3;
        float v = 0.f;
        #pragma unroll
        for (int r = 0; r < 8; ++r) v += acc8[r * 80 + node * 5 + st];
        part[bid * 64 + tid] = v;
    }
}

// ------- Kernel 2: fused graph stage (redundant per block) + broadcast scale
__global__ __launch_bounds__(256) void k_graph_scale(
    const float* __restrict__ part, const int* __restrict__ src,
    const int* __restrict__ dst,  const float* __restrict__ convb,
    const float* __restrict__ W1, const float* __restrict__ b1,
    const float* __restrict__ W2, const float* __restrict__ b2,
    const float* __restrict__ fcw, const float* __restrict__ fcb,
    const float* __restrict__ Bfon, float* __restrict__ out)
{
    const int b    = blockIdx.x / SBPB;
    const int blkb = blockIdx.x % SBPB;
    const int tid  = threadIdx.x;

    __shared__ float X[NN][4];
    __shared__ float A[NN][NN];
    __shared__ float nrm[NN];
    __shared__ float h1s[NN][32];
    __shared__ float agg[NN][32];
    __shared__ float gpart[2][COUT];
    __shared__ float Gs[COUT];

    // ---- Phase A: tiny graph network (redundant across SBPB blocks) ----
    if (tid < 64) {        // reduce the 8 channel-group partials of image b
        float v = 0.f;
        #pragma unroll
        for (int j = 0; j < NCG; ++j) v += part[(b * NCG + j) * 64 + tid];
        X[tid >> 2][tid & 3] = v;
    }
    for (int i = tid; i < NN * NN; i += 256) ((float*)A)[i] = 0.f;
    __syncthreads();

    if (tid < NN) {        // raw sums -> features (conv bias folded in)
        const float cnt = X[tid][3];
        const float cs  = fmaxf(cnt, 1.f);
        X[tid][0] = X[tid][0] / cs;
        X[tid][1] = X[tid][1] / cs;
        X[tid][2] = (X[tid][2] + cnt * convb[0]) / cs;
    }
    __syncthreads();

    // normalize feature cols 2,3 across nodes (mean, std ddof=1)
    if (tid < 2) {
        const int c = 2 + tid;
        float mu = 0.f;
        for (int i = 0; i < NN; ++i) mu += X[i][c];
        mu *= (1.f / NN);
        float var = 0.f;
        for (int i = 0; i < NN; ++i) { const float d = X[i][c] - mu; var = fmaf(d, d, var); }
        var *= (1.f / (NN - 1));
        const float inv = 1.f / (sqrtf(var) + 1.f);
        for (int i = 0; i < NN; ++i) X[i][c] = (X[i][c] - mu) * inv;
    }
    // build adjacency (idempotent set-to-1)
    if (tid >= 64 && tid < 64 + NE) {
        const int e = tid - 64;
        const int s = src[b * NE + e], d = dst[b * NE + e];
        A[s][d] = 1.f;
        A[d][s] = 1.f;
    }
    __syncthreads();

    if (tid < NN) {
        float rs = 0.f;
        for (int j = 0; j < NN; ++j) rs += A[tid][j];
        nrm[tid] = 1.f / sqrtf(fmaxf(rs, 1.f));
    }
    __syncthreads();

    if (tid < NN * 4) {    // agg1 (16x4)
        const int i = tid >> 2, k = tid & 3;
        float s = 0.f;
        for (int j = 0; j < NN; ++j) s = fmaf(A[i][j] * nrm[j], X[j][k], s);
        agg[i][k] = s;
    }
    __syncthreads();

    for (int t = tid; t < NN * 32; t += 256) {   // h1 (16x32)
        const int i = t >> 5, f = t & 31;
        float s = 0.f;
        #pragma unroll
        for (int k = 0; k < 4; ++k) s = fmaf(agg[i][k], W1[k * 32 + f], s);
        h1s[i][f] = fmaxf(fmaf(nrm[i], s, b1[f]), 0.f);
    }
    __syncthreads();

    for (int t = tid; t < NN * 32; t += 256) {   // agg2 (16x32)
        const int i = t >> 5, k = t & 31;
        float s = 0.f;
        for (int j = 0; j < NN; ++j) s = fmaf(A[i][j] * nrm[j], h1s[j][k], s);
        agg[i][k] = s;
    }
    __syncthreads();

    {   // h2 + FC, i-range split across 2 half-blocks
        const int f = tid & 127, half = tid >> 7;
        float g = 0.f;
        const float bf = b2[f];
        for (int i = half * 8; i < half * 8 + 8; ++i) {
            float s = 0.f;
            #pragma unroll
            for (int k = 0; k < 32; ++k) s = fmaf(agg[i][k], W2[k * COUT + f], s);
            g = fmaf(fcw[i], fmaxf(fmaf(nrm[i], s, bf), 0.f), g);
        }
        gpart[half][f] = g;
    }
    __syncthreads();
    if (tid < COUT) Gs[tid] = gpart[0][tid] + gpart[1][tid] + fcb[0];
    __syncthreads();

    // ---- Phase B: out[b,c,:,:] = Gs[c] * B_fon[b,c,:,:] (this block's slice)
    const float4* bf4 = reinterpret_cast<const float4*>(Bfon) + (size_t)b * PF4;
    float4*       ob4 = reinterpret_cast<float4*>(out)        + (size_t)b * PF4;
    for (int t = blkb * 256 + tid; t < PF4; t += SBPB * 256) {
        const float4 v = bf4[t];
        const float  g = Gs[t / (HW2 / 4)];   // 784 float4 per (b,c) plane
        ob4[t] = make_float4(v.x * g, v.y * g, v.z * g, v.w * g);
    }
}

extern "C" void kernel_launch(void* const* d_in, const int* in_sizes, int n_in,
                              void* d_out, int out_size, void* d_ws, size_t ws_size,
                              hipStream_t stream)
{
    const float* Bfor  = (const float*)d_in[0];
    const float* Bfon  = (const float*)d_in[1];
    const int*   seg   = (const int*)d_in[2];
    const int*   src   = (const int*)d_in[3];
    const int*   dst   = (const int*)d_in[4];
    const float* convw = (const float*)d_in[5];
    const float* convb = (const float*)d_in[6];
    const float* W1    = (const float*)d_in[7];
    const float* b1    = (const float*)d_in[8];
    const float* W2    = (const float*)d_in[9];
    const float* b2    = (const float*)d_in[10];
    const float* fcw   = (const float*)d_in[11];
    const float* fcb   = (const float*)d_in[12];

    float* part = (float*)d_ws;           // 256 blocks x 64 floats = 64 KB
    float* out  = (float*)d_out;

    k_conv_seg<<<BB * NCG, 256, 0, stream>>>(Bfor, seg, convw, part);
    k_graph_scale<<<BB * SBPB, 256, 0, stream>>>(part, src, dst, convb,
                                                 W1, b1, W2, b2, fcw, fcb,
                                                 Bfon, out);
}

// Round 9
// 47.748 us; speedup vs baseline: 1.7483x; 1.5194x over previous
//
#include <hip/hip_runtime.h>

#define NN 16
constexpr int BB = 32, CIN = 64, HH = 112, WW = 112;
constexpr int HWC = HH * WW;          // 12544
constexpr int COUT = 128, HW2 = 56 * 56;
constexpr int NE = 64;
constexpr int NQ = HWC / 4;           // 3136 float4 pixels per image
constexpr int QPB = 64;               // pixel-quads per conv block
constexpr int BPI = NQ / QPB;         // 49 conv blocks per image (exact)
constexpr int PF4 = COUT * HW2 / 4;   // 100352 float4 per batch
constexpr int SBPB = 28;              // scale blocks per batch (28*3584 = PF4)
constexpr int JPT = 14;               // float4 iters per k2 thread (14*256=3584)
constexpr int PREF = 6;               // register prefetch depth

// ---------------- Kernel 1: 1x1 conv (channel-split) + segment scatter -----
// (R3 version verbatim — best measured: total 48.8 with this k1.)
__global__ __launch_bounds__(256) void k_conv_seg(
    const float* __restrict__ Bfor, const int* __restrict__ seg,
    const float* __restrict__ convw, float* __restrict__ part)
{
    __shared__ float w[CIN];
    __shared__ float ps[4 * QPB * 5];   // [cg][quad][px], px stride 5 (bank skew)
    __shared__ float acc[8 * 80];       // [replica][node*5+st], skewed banks
    const int tid = threadIdx.x;
    const int b   = blockIdx.x / BPI;
    const int blk = blockIdx.x % BPI;
    const int cg  = tid >> 6;           // channel group == wave id
    const int l   = tid & 63;           // quad lane

    if (tid < CIN) w[tid] = convw[tid];
    for (int i = tid; i < 8 * 80; i += 256) acc[i] = 0.f;
    __syncthreads();

    const int q = blk * QPB + l;        // < 3136 always (exact tiling)
    const int p = q * 4;
    const float* base = Bfor + (size_t)b * CIN * HWC + (size_t)(cg * 16) * HWC + p;

    float4 s = make_float4(0.f, 0.f, 0.f, 0.f);
    #pragma unroll
    for (int cc = 0; cc < 16; ++cc) {
        const float4 v = *reinterpret_cast<const float4*>(base + (size_t)cc * HWC);
        const float wc = w[cg * 16 + cc];
        s.x = fmaf(v.x, wc, s.x);
        s.y = fmaf(v.y, wc, s.y);
        s.z = fmaf(v.z, wc, s.z);
        s.w = fmaf(v.w, wc, s.w);
    }
    ps[cg * 320 + l * 5 + 0] = s.x;
    ps[cg * 320 + l * 5 + 1] = s.y;
    ps[cg * 320 + l * 5 + 2] = s.z;
    ps[cg * 320 + l * 5 + 3] = s.w;
    __syncthreads();

    if (tid < 64) {
        float r0 = 0.f, r1 = 0.f, r2 = 0.f, r3 = 0.f;
        #pragma unroll
        for (int g = 0; g < 4; ++g) {
            r0 += ps[g * 320 + tid * 5 + 0];
            r1 += ps[g * 320 + tid * 5 + 1];
            r2 += ps[g * 320 + tid * 5 + 2];
            r3 += ps[g * 320 + tid * 5 + 3];
        }
        const int pp = (blk * QPB + tid) * 4;
        const int4 sg = *reinterpret_cast<const int4*>(seg + (size_t)b * HWC + pp);
        const float row  = (float)(pp / WW);   // WW%4==0 -> all 4 px same row
        const float col0 = (float)(pp % WW);
        const int k = tid & 7;                 // replica
        atomicAdd(&acc[k * 80 + sg.x * 5 + 0], row);
        atomicAdd(&acc[k * 80 + sg.x * 5 + 1], col0);
        atomicAdd(&acc[k * 80 + sg.x * 5 + 2], r0);
        atomicAdd(&acc[k * 80 + sg.x * 5 + 3], 1.f);
        atomicAdd(&acc[k * 80 + sg.y * 5 + 0], row);
        atomicAdd(&acc[k * 80 + sg.y * 5 + 1], col0 + 1.f);
        atomicAdd(&acc[k * 80 + sg.y * 5 + 2], r1);
        atomicAdd(&acc[k * 80 + sg.y * 5 + 3], 1.f);
        atomicAdd(&acc[k * 80 + sg.z * 5 + 0], row);
        atomicAdd(&acc[k * 80 + sg.z * 5 + 1], col0 + 2.f);
        atomicAdd(&acc[k * 80 + sg.z * 5 + 2], r2);
        atomicAdd(&acc[k * 80 + sg.z * 5 + 3], 1.f);
        atomicAdd(&acc[k * 80 + sg.w * 5 + 0], row);
        atomicAdd(&acc[k * 80 + sg.w * 5 + 1], col0 + 3.f);
        atomicAdd(&acc[k * 80 + sg.w * 5 + 2], r3);
        atomicAdd(&acc[k * 80 + sg.w * 5 + 3], 1.f);
    }
    __syncthreads();

    if (tid < NN * 4) {
        const int node = tid >> 2, st = tid & 3;
        float v = 0.f;
        #pragma unroll
        for (int k = 0; k < 8; ++k) v += acc[k * 80 + node * 5 + st];
        part[((b * BPI + blk) * NN + node) * 4 + st] = v;
    }
}

// ------- Kernel 2: fused graph stage + scale, with Bfon register prefetch
// issued BEFORE Phase A so HBM streams during the graph-network bubble.
__global__ __launch_bounds__(256) void k_graph_scale(
    const float* __restrict__ part, const int* __restrict__ src,
    const int* __restrict__ dst,  const float* __restrict__ convb,
    const float* __restrict__ W1, const float* __restrict__ b1,
    const float* __restrict__ W2, const float* __restrict__ b2,
    const float* __restrict__ fcw, const float* __restrict__ fcb,
    const float* __restrict__ Bfon, float* __restrict__ out)
{
    const int b    = blockIdx.x / SBPB;
    const int blkb = blockIdx.x % SBPB;
    const int tid  = threadIdx.x;
    const int w0   = blkb * (JPT * 256);   // contiguous window in [0, PF4)

    __shared__ float X[NN][4];
    __shared__ float A[NN][NN];
    __shared__ float nrm[NN];
    __shared__ float h1s[NN][32];
    __shared__ float agg[NN][32];
    __shared__ float gpart[2][COUT];
    __shared__ float Gs[COUT];

    const float4* bf4 = reinterpret_cast<const float4*>(Bfon) + (size_t)b * PF4;
    float4*       ob4 = reinterpret_cast<float4*>(out)        + (size_t)b * PF4;

    // ---- issue Bfon prefetch (depth PREF) before Phase A ----
    float4 r[JPT];
    #pragma unroll
    for (int j = 0; j < PREF; ++j) r[j] = bf4[w0 + j * 256 + tid];

    // ---- Phase A: tiny graph network (redundant across SBPB blocks) ----
    if (tid < 64) {        // reduce 49 conv-block partials, coalesced per iter
        const int node = tid >> 2, st = tid & 3;
        float v = 0.f;
        for (int k = 0; k < BPI; ++k) v += part[((b * BPI + k) * NN + node) * 4 + st];
        X[node][st] = v;
    }
    for (int i = tid; i < NN * NN; i += 256) ((float*)A)[i] = 0.f;
    __syncthreads();

    if (tid < NN) {        // raw sums -> features (conv bias folded in)
        const float cnt = X[tid][3];
        const float cs  = fmaxf(cnt, 1.f);
        X[tid][0] = X[tid][0] / cs;
        X[tid][1] = X[tid][1] / cs;
        X[tid][2] = (X[tid][2] + cnt * convb[0]) / cs;
    }
    __syncthreads();

    // normalize feature cols 2,3 across nodes (mean, std ddof=1)
    if (tid < 2) {
        const int c = 2 + tid;
        float mu = 0.f;
        for (int i = 0; i < NN; ++i) mu += X[i][c];
        mu *= (1.f / NN);
        float var = 0.f;
        for (int i = 0; i < NN; ++i) { const float d = X[i][c] - mu; var = fmaf(d, d, var); }
        var *= (1.f / (NN - 1));
        const float inv = 1.f / (sqrtf(var) + 1.f);
        for (int i = 0; i < NN; ++i) X[i][c] = (X[i][c] - mu) * inv;
    }
    // build adjacency (idempotent set-to-1)
    if (tid >= 64 && tid < 64 + NE) {
        const int e = tid - 64;
        const int s = src[b * NE + e], d = dst[b * NE + e];
        A[s][d] = 1.f;
        A[d][s] = 1.f;
    }
    __syncthreads();

    if (tid < NN) {
        float rs = 0.f;
        for (int j = 0; j < NN; ++j) rs += A[tid][j];
        nrm[tid] = 1.f / sqrtf(fmaxf(rs, 1.f));
    }
    __syncthreads();

    if (tid < NN * 4) {    // agg1 (16x4)
        const int i = tid >> 2, k = tid & 3;
        float s = 0.f;
        for (int j = 0; j < NN; ++j) s = fmaf(A[i][j] * nrm[j], X[j][k], s);
        agg[i][k] = s;
    }
    __syncthreads();

    for (int t = tid; t < NN * 32; t += 256) {   // h1 (16x32)
        const int i = t >> 5, f = t & 31;
        float s = 0.f;
        #pragma unroll
        for (int k = 0; k < 4; ++k) s = fmaf(agg[i][k], W1[k * 32 + f], s);
        h1s[i][f] = fmaxf(fmaf(nrm[i], s, b1[f]), 0.f);
    }
    __syncthreads();

    for (int t = tid; t < NN * 32; t += 256) {   // agg2 (16x32)
        const int i = t >> 5, k = t & 31;
        float s = 0.f;
        for (int j = 0; j < NN; ++j) s = fmaf(A[i][j] * nrm[j], h1s[j][k], s);
        agg[i][k] = s;
    }
    __syncthreads();

    {   // h2 + FC, i-range split across 2 half-blocks
        const int f = tid & 127, half = tid >> 7;
        float g = 0.f;
        const float bf = b2[f];
        for (int i = half * 8; i < half * 8 + 8; ++i) {
            float s = 0.f;
            #pragma unroll
            for (int k = 0; k < 32; ++k) s = fmaf(agg[i][k], W2[k * COUT + f], s);
            g = fmaf(fcw[i], fmaxf(fmaf(nrm[i], s, bf), 0.f), g);
        }
        gpart[half][f] = g;
    }
    __syncthreads();
    if (tid < COUT) Gs[tid] = gpart[0][tid] + gpart[1][tid] + fcb[0];
    __syncthreads();

    // ---- Phase B: rolling register pipeline over the contiguous window ----
    #pragma unroll
    for (int j = 0; j < JPT; ++j) {
        if (j + PREF < JPT) r[j + PREF] = bf4[w0 + (j + PREF) * 256 + tid];
        const int t = w0 + j * 256 + tid;
        const float g = Gs[t / (HW2 / 4)];   // 784 float4 per (b,c) plane
        ob4[t] = make_float4(r[j].x * g, r[j].y * g, r[j].z * g, r[j].w * g);
    }
}

extern "C" void kernel_launch(void* const* d_in, const int* in_sizes, int n_in,
                              void* d_out, int out_size, void* d_ws, size_t ws_size,
                              hipStream_t stream)
{
    const float* Bfor  = (const float*)d_in[0];
    const float* Bfon  = (const float*)d_in[1];
    const int*   seg   = (const int*)d_in[2];
    const int*   src   = (const int*)d_in[3];
    const int*   dst   = (const int*)d_in[4];
    const float* convw = (const float*)d_in[5];
    const float* convb = (const float*)d_in[6];
    const float* W1    = (const float*)d_in[7];
    const float* b1    = (const float*)d_in[8];
    const float* W2    = (const float*)d_in[9];
    const float* b2    = (const float*)d_in[10];
    const float* fcw   = (const float*)d_in[11];
    const float* fcb   = (const float*)d_in[12];

    float* part = (float*)d_ws;           // BB*BPI*NN*4 floats = 401 KB
    float* out  = (float*)d_out;

    k_conv_seg<<<BB * BPI, 256, 0, stream>>>(Bfor, seg, convw, part);
    k_graph_scale<<<BB * SBPB, 256, 0, stream>>>(part, src, dst, convb,
                                                 W1, b1, W2, b2, fcw, fcb,
                                                 Bfon, out);
}